// Round 9
// baseline (164.049 us; speedup 1.0000x reference)
//
#include <hip/hip_runtime.h>

#define BATCH 128
#define H 224
#define W 224
#define PH1 112
#define PH2 56
#define FLAT (PH2*PH2*10)   // 31360
#define KC 64               // fc1 K-chunk

// ---------------- Kernel A: conv1(3x3,3->8,SAME)+bias+relu+maxpool2, LDS-tiled ----------------
// v2: block = 2 pooled rows x 112 cols (224 active threads of 256).
// Input slab staged in LDS channel-planar [3][6][228] (pad col each side, zeroed);
// staging via 1008 coalesced float4 loads. Weights/bias read with wave-uniform
// indices directly from global -> SGPR (s_load), no LDS weight traffic.
#define C1R 6
#define C1C 228
__global__ __launch_bounds__(256) void k_conv1(const float* __restrict__ x,
        const float* __restrict__ w, const float* __restrict__ bias,
        float* __restrict__ pool1) {
    __shared__ float lds[3*C1R*C1C];   // 4104 f = 16.4 KB
    int tid = threadIdx.x;
    int rg = blockIdx.x % 56;          // pooled rows 2*rg, 2*rg+1
    int b  = blockIdx.x / 56;

    // zero pad columns 0 and 225..227
    if (tid < 72) {
        int ch = tid / 24, rem = tid % 24;
        int r = rem / 4, c4 = rem % 4;
        int col = (c4 == 0) ? 0 : (224 + c4);
        lds[(ch*C1R + r)*C1C + col] = 0.f;
    }
    // stage 6 input rows (4*rg-1 .. 4*rg+4), 672 f each, as 168 float4/row
    int row0 = 4*rg - 1;
    const float* xb = x + (size_t)b*H*W*3;
    for (int i = tid; i < 1008; i += 256) {
        int r = i / 168, f4 = i % 168;
        int iy = row0 + r;
        float4 v = make_float4(0.f,0.f,0.f,0.f);
        if (iy >= 0 && iy < H)
            v = *(const float4*)(xb + (size_t)iy*672 + f4*4);
        int fl = f4*4;
        float vv[4] = {v.x, v.y, v.z, v.w};
        #pragma unroll
        for (int c = 0; c < 4; ++c) {
            int f = fl + c;
            int px = f / 3, ch = f - 3*px;
            lds[(ch*C1R + r)*C1C + (px+1)] = vv[c];
        }
    }
    __syncthreads();

    if (tid >= 224) return;
    int dpr = tid >> 7, pc = tid & 127;      // dpr 0..1, pc 0..111 (tid<224 so pc<112 when dpr=1)
    // NOTE: tid 0..111 -> dpr 0, pc 0..111 ; tid 128..223 -> dpr 1, pc 0..95 ... WRONG split.
    // Use clean div instead:
    dpr = tid / 112; pc = tid % 112;

    float acc[4][8];
    #pragma unroll
    for (int p = 0; p < 4; ++p)
        #pragma unroll
        for (int co = 0; co < 8; ++co) acc[p][co] = bias[co];   // uniform -> SGPR

    #pragma unroll
    for (int ci = 0; ci < 3; ++ci) {
        // 4x4 window for this channel: slab rows 2*dpr..2*dpr+3, cols 2*pc..2*pc+3 (even base)
        float v[4][4];
        #pragma unroll
        for (int rr = 0; rr < 4; ++rr) {
            const float2* lp2 = (const float2*)(lds + ((size_t)(ci*C1R + 2*dpr + rr))*C1C + 2*pc);
            float2 a = lp2[0], c2 = lp2[1];
            v[rr][0] = a.x; v[rr][1] = a.y; v[rr][2] = c2.x; v[rr][3] = c2.y;
        }
        #pragma unroll
        for (int ky = 0; ky < 3; ++ky)
        #pragma unroll
        for (int kx = 0; kx < 3; ++kx) {
            const float* wp = &w[((ky*3+kx)*3+ci)*8];   // uniform -> s_load
            float wv[8];
            #pragma unroll
            for (int co = 0; co < 8; ++co) wv[co] = wp[co];
            #pragma unroll
            for (int cy = 0; cy < 2; ++cy)
            #pragma unroll
            for (int cx = 0; cx < 2; ++cx) {
                float vin = v[cy+ky][cx+kx];
                #pragma unroll
                for (int co = 0; co < 8; ++co)
                    acc[cy*2+cx][co] = fmaf(vin, wv[co], acc[cy*2+cx][co]);
            }
        }
    }

    float pooled[8];
    #pragma unroll
    for (int co = 0; co < 8; ++co)
        pooled[co] = fmaxf(fmaxf(fmaxf(fmaxf(0.f, acc[0][co]), acc[1][co]), acc[2][co]), acc[3][co]);
    int pr = 2*rg + dpr;
    float4* o4 = (float4*)(pool1 + ((size_t)((b*PH1 + pr)*PH1 + pc))*8);
    o4[0] = make_float4(pooled[0], pooled[1], pooled[2], pooled[3]);
    o4[1] = make_float4(pooled[4], pooled[5], pooled[6], pooled[7]);
}

// ---------------- Kernel B: conv2(3x3,8->10,SAME)+bias+relu+maxpool2, LDS-tiled ----------------
#define C2_ROWS 10
#define C2_COLS 114
#define C2_PLANE (C2_ROWS*C2_COLS)   // 1140
__global__ __launch_bounds__(256) void k_conv2(const float* __restrict__ pool1,
        const float* __restrict__ w, const float* __restrict__ bias,
        float* __restrict__ pool2) {
    __shared__ float lds[8*C2_PLANE];   // 9120 f = 36.5 KB
    __shared__ float ws[720];
    __shared__ float bs[10];
    int tid = threadIdx.x;
    int rg = blockIdx.x % 14;           // row group: pooled rows 4*rg .. 4*rg+3
    int b  = blockIdx.x / 14;

    for (int i = tid; i < 720; i += 256) ws[i] = w[i];
    if (tid < 10) bs[tid] = bias[tid];
    if (tid < 160) {
        int ci = tid / 20, rem = tid % 20;
        int r = rem >> 1, col = (rem & 1) ? (C2_COLS-1) : 0;
        lds[ci*C2_PLANE + r*C2_COLS + col] = 0.f;
    }
    int row0 = 8*rg - 1;
    for (int i = tid; i < 2240; i += 256) {
        int r = i / 224, rem = i % 224;
        int pix = rem >> 1, half = rem & 1;
        int iy = row0 + r;
        float4 v = make_float4(0.f,0.f,0.f,0.f);
        if (iy >= 0 && iy < PH1)
            v = *(const float4*)(pool1 + ((size_t)((b*PH1 + iy)*PH1 + pix))*8 + half*4);
        float* dst = lds + (half*4)*C2_PLANE + r*C2_COLS + (pix+1);
        dst[0*C2_PLANE] = v.x;
        dst[1*C2_PLANE] = v.y;
        dst[2*C2_PLANE] = v.z;
        dst[3*C2_PLANE] = v.w;
    }
    __syncthreads();

    if (tid >= 224) return;
    int dpr = tid / 56, pc = tid % 56;
    int rbase = 2*dpr;
    int cbase = 2*pc;

    float acc[4][10];
    #pragma unroll
    for (int p = 0; p < 4; ++p)
        #pragma unroll
        for (int co = 0; co < 10; ++co) acc[p][co] = bs[co];

    #pragma unroll
    for (int ci = 0; ci < 8; ++ci) {
        float v[4][4];
        #pragma unroll
        for (int r = 0; r < 4; ++r) {
            const float2* lp2 = (const float2*)(lds + ci*C2_PLANE + (rbase+r)*C2_COLS + cbase);
            float2 a = lp2[0], c = lp2[1];
            v[r][0] = a.x; v[r][1] = a.y; v[r][2] = c.x; v[r][3] = c.y;
        }
        #pragma unroll
        for (int ky = 0; ky < 3; ++ky)
        #pragma unroll
        for (int kx = 0; kx < 3; ++kx) {
            const float* wp = &ws[((ky*3+kx)*8+ci)*10];
            float wv[10];
            #pragma unroll
            for (int co = 0; co < 10; ++co) wv[co] = wp[co];
            #pragma unroll
            for (int cy = 0; cy < 2; ++cy)
            #pragma unroll
            for (int cx = 0; cx < 2; ++cx) {
                float vv = v[cy+ky][cx+kx];
                #pragma unroll
                for (int co = 0; co < 10; ++co)
                    acc[cy*2+cx][co] = fmaf(vv, wv[co], acc[cy*2+cx][co]);
            }
        }
    }

    float pooled[10];
    #pragma unroll
    for (int co = 0; co < 10; ++co)
        pooled[co] = fmaxf(fmaxf(fmaxf(fmaxf(0.f, acc[0][co]), acc[1][co]), acc[2][co]), acc[3][co]);
    int pr = 4*rg + dpr;
    float2* o2 = (float2*)(pool2 + ((size_t)(b*PH2 + pr)*PH2 + pc)*10);
    #pragma unroll
    for (int i = 0; i < 5; ++i) o2[i] = make_float2(pooled[2*i], pooled[2*i+1]);
}

// ---------------- Kernel C: fc1 split-K partial GEMM (atomics into t_raw) ----------------
__global__ __launch_bounds__(256) void k_fc1(const float* __restrict__ pool2,
        const float* __restrict__ w, float* __restrict__ t_raw) {
    __shared__ float Ash[BATCH][KC];   // 32 KB
    __shared__ float Wsh[KC][32];      // 8 KB
    int tid = threadIdx.x;
    int k0 = blockIdx.x * KC;          // 490 blocks, 490*64 = 31360
    for (int i = tid; i < KC*32; i += 256) {
        int k = i >> 5, n = i & 31;
        Wsh[k][n] = w[(size_t)(k0 + k)*32 + n];
    }
    {
        int k = tid & 63, br = tid >> 6;
        for (int p = 0; p < 32; ++p) {
            int b = p*4 + br;
            Ash[b][k] = pool2[(size_t)b*FLAT + k0 + k];
        }
    }
    __syncthreads();
    int n = tid & 31, bg = tid >> 5;
    for (int bo = 0; bo < 16; ++bo) {
        int b = bo*8 + bg;
        float acc = 0.f;
        #pragma unroll
        for (int k = 0; k < KC; ++k) acc = fmaf(Ash[b][k], Wsh[k][n], acc);
        atomicAdd(&t_raw[b*32 + n], acc);
    }
}

// ---------------- Kernel D: relu(t+fc1_b) @ fc2_w + fc2_b -> theta [128,6] ----------------
__global__ __launch_bounds__(128) void k_fc2(const float* __restrict__ t_raw,
        const float* __restrict__ fc1_b,
        const float* __restrict__ w, const float* __restrict__ bias,
        float* __restrict__ theta) {
    int b = threadIdx.x;  // 128 threads, 1 block
    float acc[6];
    #pragma unroll
    for (int j = 0; j < 6; ++j) acc[j] = bias[j];
    for (int i = 0; i < 32; ++i) {
        float t = fmaxf(t_raw[b*32 + i] + fc1_b[i], 0.f);
        #pragma unroll
        for (int j = 0; j < 6; ++j) acc[j] = fmaf(t, w[i*6 + j], acc[j]);
    }
    #pragma unroll
    for (int j = 0; j < 6; ++j) theta[b*6 + j] = acc[j];
}

// ---------------- Kernel E: affine grid + bilinear sample (exact ref semantics) ----------------
__global__ __launch_bounds__(256) void k_sample(const float* __restrict__ x,
        const float* __restrict__ theta, float* __restrict__ out) {
    int gid = blockIdx.x * 256 + threadIdx.x;   // 128*224*224 = 6,422,528
    int wi = gid % W;
    int t2 = gid / W;
    int hi = t2 % H;
    int b  = t2 / H;
    const float* th = theta + b*6;
    float xt = -1.0f + wi * (2.0f/223.0f);
    float yt = -1.0f + hi * (2.0f/223.0f);
    float gx = th[0]*xt + th[1]*yt + th[2];
    float gy = th[3]*xt + th[4]*yt + th[5];
    float x_s = (gx + 1.0f) * 0.5f * 223.0f;
    float y_s = (gy + 1.0f) * 0.5f * 223.0f;
    int x0 = min(max((int)floorf(x_s), 0), W-1);
    int x1 = min(x0 + 1, W-1);
    int y0 = min(max((int)floorf(y_s), 0), H-1);
    int y1 = min(y0 + 1, H-1);
    float x0f = (float)x0, x1f = (float)x1, y0f = (float)y0, y1f = (float)y1;
    float wa = (x1f - x_s) * (y1f - y_s);
    float wb = (x1f - x_s) * (y_s - y0f);
    float wc = (x_s - x0f) * (y1f - y_s);
    float wd = (x_s - x0f) * (y_s - y0f);
    const float* base = x + (size_t)b*H*W*3;
    const float* p00 = base + (size_t)(y0*W + x0)*3;
    const float* p01 = base + (size_t)(y1*W + x0)*3;
    const float* p10 = base + (size_t)(y0*W + x1)*3;
    const float* p11 = base + (size_t)(y1*W + x1)*3;
    float* o = out + (size_t)gid*3;
    #pragma unroll
    for (int c = 0; c < 3; ++c)
        o[c] = wa*p00[c] + wb*p01[c] + wc*p10[c] + wd*p11[c];
}

extern "C" void kernel_launch(void* const* d_in, const int* in_sizes, int n_in,
                              void* d_out, int out_size, void* d_ws, size_t ws_size,
                              hipStream_t stream) {
    const float* x       = (const float*)d_in[0];
    const float* conv1_w = (const float*)d_in[1];
    const float* conv1_b = (const float*)d_in[2];
    const float* conv2_w = (const float*)d_in[3];
    const float* conv2_b = (const float*)d_in[4];
    const float* fc1_w   = (const float*)d_in[5];
    const float* fc1_b   = (const float*)d_in[6];
    const float* fc2_w   = (const float*)d_in[7];
    const float* fc2_b   = (const float*)d_in[8];
    float* out = (float*)d_out;

    // Scratch layout: pool1 + pool2 live INSIDE d_out (fully consumed before the
    // sampler overwrites d_out). d_ws holds only fc activations (~20 KB).
    float* pool1 = out;
    float* pool2 = out + 12845056;
    float* t_raw = (float*)d_ws;            // 128*32 f32
    float* theta = t_raw + BATCH*32;        // 128*6  f32

    hipMemsetAsync(t_raw, 0, BATCH*32*sizeof(float), stream);
    k_conv1<<<7168, 256, 0, stream>>>(x, conv1_w, conv1_b, pool1);
    k_conv2<<<1792, 256, 0, stream>>>(pool1, conv2_w, conv2_b, pool2);
    k_fc1<<<490, 256, 0, stream>>>(pool2, fc1_w, t_raw);
    k_fc2<<<1, 128, 0, stream>>>(t_raw, fc1_b, fc2_w, fc2_b, theta);
    k_sample<<<25088, 256, 0, stream>>>(x, theta, out);
}

// Round 10
// 145.780 us; speedup vs baseline: 1.1253x; 1.1253x over previous
//
#include <hip/hip_runtime.h>

#define BATCH 128
#define H 224
#define W 224
#define PH1 112
#define PH2 56
#define FLAT (PH2*PH2*10)   // 31360
#define KC 64               // fc1 K-chunk

// ---------------- Kernel A: conv1(3x3,3->8,SAME)+bias+relu+maxpool2 ----------------
// v3 = round-4 structure (direct global window loads, weights in LDS) with:
//  (1) __launch_bounds__(256,4): VGPR cap 128 so in[48]+acc[32]+wv[8] stay live
//      (VGPR=48 build was rematerializing window loads — measured 57us).
//  (2) ci/ky/kx-outer loop order, wv[8] hoisted once per (ky,kx,ci) feeding all
//      4 conv positions: 216 weight LDS reads instead of 864 (conv2-v2 fix).
__global__ __launch_bounds__(256, 4) void k_conv1(const float* __restrict__ x,
        const float* __restrict__ w, const float* __restrict__ bias,
        float* __restrict__ pool1) {
    __shared__ float ws[216];
    __shared__ float bs[8];
    int tid = threadIdx.x;
    if (tid < 216) ws[tid] = w[tid];
    if (tid < 8) bs[tid] = bias[tid];
    __syncthreads();
    int gid = blockIdx.x * 256 + tid;      // 128*112*112 = 1,605,632 total
    int pw = gid % PH1;
    int t2 = gid / PH1;
    int ph = t2 % PH1;
    int b  = t2 / PH1;

    float in[4][4][3];
    #pragma unroll
    for (int r = 0; r < 4; ++r) {
        int iy = 2*ph - 1 + r;
        bool yok = (iy >= 0) && (iy < H);
        #pragma unroll
        for (int cpx = 0; cpx < 4; ++cpx) {
            int ix = 2*pw - 1 + cpx;
            bool ok = yok && (ix >= 0) && (ix < W);
            const float* p = x + ((size_t)((b*H + iy)*W + ix))*3;
            in[r][cpx][0] = ok ? p[0] : 0.f;
            in[r][cpx][1] = ok ? p[1] : 0.f;
            in[r][cpx][2] = ok ? p[2] : 0.f;
        }
    }

    float acc[4][8];
    #pragma unroll
    for (int p = 0; p < 4; ++p)
        #pragma unroll
        for (int co = 0; co < 8; ++co) acc[p][co] = bs[co];

    #pragma unroll
    for (int ci = 0; ci < 3; ++ci)
    #pragma unroll
    for (int ky = 0; ky < 3; ++ky)
    #pragma unroll
    for (int kx = 0; kx < 3; ++kx) {
        const float* wp = &ws[((ky*3+kx)*3+ci)*8];
        float wv[8];
        #pragma unroll
        for (int co = 0; co < 8; ++co) wv[co] = wp[co];
        #pragma unroll
        for (int cy = 0; cy < 2; ++cy)
        #pragma unroll
        for (int cx = 0; cx < 2; ++cx) {
            float vin = in[cy+ky][cx+kx][ci];
            #pragma unroll
            for (int co = 0; co < 8; ++co)
                acc[cy*2+cx][co] = fmaf(vin, wv[co], acc[cy*2+cx][co]);
        }
    }

    float pooled[8];
    #pragma unroll
    for (int co = 0; co < 8; ++co)
        pooled[co] = fmaxf(fmaxf(fmaxf(fmaxf(0.f, acc[0][co]), acc[1][co]), acc[2][co]), acc[3][co]);
    float4* o4 = (float4*)(pool1 + (size_t)gid*8);
    o4[0] = make_float4(pooled[0], pooled[1], pooled[2], pooled[3]);
    o4[1] = make_float4(pooled[4], pooled[5], pooled[6], pooled[7]);
}

// ---------------- Kernel B: conv2(3x3,8->10,SAME)+bias+relu+maxpool2, LDS-tiled ----------------
#define C2_ROWS 10
#define C2_COLS 114
#define C2_PLANE (C2_ROWS*C2_COLS)   // 1140
__global__ __launch_bounds__(256) void k_conv2(const float* __restrict__ pool1,
        const float* __restrict__ w, const float* __restrict__ bias,
        float* __restrict__ pool2) {
    __shared__ float lds[8*C2_PLANE];   // 9120 f = 36.5 KB
    __shared__ float ws[720];
    __shared__ float bs[10];
    int tid = threadIdx.x;
    int rg = blockIdx.x % 14;           // row group: pooled rows 4*rg .. 4*rg+3
    int b  = blockIdx.x / 14;

    for (int i = tid; i < 720; i += 256) ws[i] = w[i];
    if (tid < 10) bs[tid] = bias[tid];
    if (tid < 160) {
        int ci = tid / 20, rem = tid % 20;
        int r = rem >> 1, col = (rem & 1) ? (C2_COLS-1) : 0;
        lds[ci*C2_PLANE + r*C2_COLS + col] = 0.f;
    }
    int row0 = 8*rg - 1;
    for (int i = tid; i < 2240; i += 256) {
        int r = i / 224, rem = i % 224;
        int pix = rem >> 1, half = rem & 1;
        int iy = row0 + r;
        float4 v = make_float4(0.f,0.f,0.f,0.f);
        if (iy >= 0 && iy < PH1)
            v = *(const float4*)(pool1 + ((size_t)((b*PH1 + iy)*PH1 + pix))*8 + half*4);
        float* dst = lds + (half*4)*C2_PLANE + r*C2_COLS + (pix+1);
        dst[0*C2_PLANE] = v.x;
        dst[1*C2_PLANE] = v.y;
        dst[2*C2_PLANE] = v.z;
        dst[3*C2_PLANE] = v.w;
    }
    __syncthreads();

    if (tid >= 224) return;
    int dpr = tid / 56, pc = tid % 56;
    int rbase = 2*dpr;
    int cbase = 2*pc;

    float acc[4][10];
    #pragma unroll
    for (int p = 0; p < 4; ++p)
        #pragma unroll
        for (int co = 0; co < 10; ++co) acc[p][co] = bs[co];

    #pragma unroll
    for (int ci = 0; ci < 8; ++ci) {
        float v[4][4];
        #pragma unroll
        for (int r = 0; r < 4; ++r) {
            const float2* lp2 = (const float2*)(lds + ci*C2_PLANE + (rbase+r)*C2_COLS + cbase);
            float2 a = lp2[0], c = lp2[1];
            v[r][0] = a.x; v[r][1] = a.y; v[r][2] = c.x; v[r][3] = c.y;
        }
        #pragma unroll
        for (int ky = 0; ky < 3; ++ky)
        #pragma unroll
        for (int kx = 0; kx < 3; ++kx) {
            const float* wp = &ws[((ky*3+kx)*8+ci)*10];
            float wv[10];
            #pragma unroll
            for (int co = 0; co < 10; ++co) wv[co] = wp[co];
            #pragma unroll
            for (int cy = 0; cy < 2; ++cy)
            #pragma unroll
            for (int cx = 0; cx < 2; ++cx) {
                float vv = v[cy+ky][cx+kx];
                #pragma unroll
                for (int co = 0; co < 10; ++co)
                    acc[cy*2+cx][co] = fmaf(vv, wv[co], acc[cy*2+cx][co]);
            }
        }
    }

    float pooled[10];
    #pragma unroll
    for (int co = 0; co < 10; ++co)
        pooled[co] = fmaxf(fmaxf(fmaxf(fmaxf(0.f, acc[0][co]), acc[1][co]), acc[2][co]), acc[3][co]);
    int pr = 4*rg + dpr;
    float2* o2 = (float2*)(pool2 + ((size_t)(b*PH2 + pr)*PH2 + pc)*10);
    #pragma unroll
    for (int i = 0; i < 5; ++i) o2[i] = make_float2(pooled[2*i], pooled[2*i+1]);
}

// ---------------- Kernel C: fc1 split-K partial GEMM (atomics into t_raw) ----------------
__global__ __launch_bounds__(256) void k_fc1(const float* __restrict__ pool2,
        const float* __restrict__ w, float* __restrict__ t_raw) {
    __shared__ float Ash[BATCH][KC];   // 32 KB
    __shared__ float Wsh[KC][32];      // 8 KB
    int tid = threadIdx.x;
    int k0 = blockIdx.x * KC;          // 490 blocks, 490*64 = 31360
    for (int i = tid; i < KC*32; i += 256) {
        int k = i >> 5, n = i & 31;
        Wsh[k][n] = w[(size_t)(k0 + k)*32 + n];
    }
    {
        int k = tid & 63, br = tid >> 6;
        for (int p = 0; p < 32; ++p) {
            int b = p*4 + br;
            Ash[b][k] = pool2[(size_t)b*FLAT + k0 + k];
        }
    }
    __syncthreads();
    int n = tid & 31, bg = tid >> 5;
    for (int bo = 0; bo < 16; ++bo) {
        int b = bo*8 + bg;
        float acc = 0.f;
        #pragma unroll
        for (int k = 0; k < KC; ++k) acc = fmaf(Ash[b][k], Wsh[k][n], acc);
        atomicAdd(&t_raw[b*32 + n], acc);
    }
}

// ---------------- Kernel D: relu(t+fc1_b) @ fc2_w + fc2_b -> theta [128,6] ----------------
__global__ __launch_bounds__(128) void k_fc2(const float* __restrict__ t_raw,
        const float* __restrict__ fc1_b,
        const float* __restrict__ w, const float* __restrict__ bias,
        float* __restrict__ theta) {
    int b = threadIdx.x;  // 128 threads, 1 block
    float acc[6];
    #pragma unroll
    for (int j = 0; j < 6; ++j) acc[j] = bias[j];
    for (int i = 0; i < 32; ++i) {
        float t = fmaxf(t_raw[b*32 + i] + fc1_b[i], 0.f);
        #pragma unroll
        for (int j = 0; j < 6; ++j) acc[j] = fmaf(t, w[i*6 + j], acc[j]);
    }
    #pragma unroll
    for (int j = 0; j < 6; ++j) theta[b*6 + j] = acc[j];
}

// ---------------- Kernel E: affine grid + bilinear sample (exact ref semantics) ----------------
__global__ __launch_bounds__(256) void k_sample(const float* __restrict__ x,
        const float* __restrict__ theta, float* __restrict__ out) {
    int gid = blockIdx.x * 256 + threadIdx.x;   // 128*224*224 = 6,422,528
    int wi = gid % W;
    int t2 = gid / W;
    int hi = t2 % H;
    int b  = t2 / H;
    const float* th = theta + b*6;
    float xt = -1.0f + wi * (2.0f/223.0f);
    float yt = -1.0f + hi * (2.0f/223.0f);
    float gx = th[0]*xt + th[1]*yt + th[2];
    float gy = th[3]*xt + th[4]*yt + th[5];
    float x_s = (gx + 1.0f) * 0.5f * 223.0f;
    float y_s = (gy + 1.0f) * 0.5f * 223.0f;
    int x0 = min(max((int)floorf(x_s), 0), W-1);
    int x1 = min(x0 + 1, W-1);
    int y0 = min(max((int)floorf(y_s), 0), H-1);
    int y1 = min(y0 + 1, H-1);
    float x0f = (float)x0, x1f = (float)x1, y0f = (float)y0, y1f = (float)y1;
    float wa = (x1f - x_s) * (y1f - y_s);
    float wb = (x1f - x_s) * (y_s - y0f);
    float wc = (x_s - x0f) * (y1f - y_s);
    float wd = (x_s - x0f) * (y_s - y0f);
    const float* base = x + (size_t)b*H*W*3;
    const float* p00 = base + (size_t)(y0*W + x0)*3;
    const float* p01 = base + (size_t)(y1*W + x0)*3;
    const float* p10 = base + (size_t)(y0*W + x1)*3;
    const float* p11 = base + (size_t)(y1*W + x1)*3;
    float* o = out + (size_t)gid*3;
    #pragma unroll
    for (int c = 0; c < 3; ++c)
        o[c] = wa*p00[c] + wb*p01[c] + wc*p10[c] + wd*p11[c];
}

extern "C" void kernel_launch(void* const* d_in, const int* in_sizes, int n_in,
                              void* d_out, int out_size, void* d_ws, size_t ws_size,
                              hipStream_t stream) {
    const float* x       = (const float*)d_in[0];
    const float* conv1_w = (const float*)d_in[1];
    const float* conv1_b = (const float*)d_in[2];
    const float* conv2_w = (const float*)d_in[3];
    const float* conv2_b = (const float*)d_in[4];
    const float* fc1_w   = (const float*)d_in[5];
    const float* fc1_b   = (const float*)d_in[6];
    const float* fc2_w   = (const float*)d_in[7];
    const float* fc2_b   = (const float*)d_in[8];
    float* out = (float*)d_out;

    // Scratch layout: pool1 + pool2 live INSIDE d_out (fully consumed before the
    // sampler overwrites d_out). d_ws holds only fc activations (~20 KB).
    float* pool1 = out;
    float* pool2 = out + 12845056;
    float* t_raw = (float*)d_ws;            // 128*32 f32
    float* theta = t_raw + BATCH*32;        // 128*6  f32

    hipMemsetAsync(t_raw, 0, BATCH*32*sizeof(float), stream);
    k_conv1<<<6272, 256, 0, stream>>>(x, conv1_w, conv1_b, pool1);
    k_conv2<<<1792, 256, 0, stream>>>(pool1, conv2_w, conv2_b, pool2);
    k_fc1<<<490, 256, 0, stream>>>(pool2, fc1_w, t_raw);
    k_fc2<<<1, 128, 0, stream>>>(t_raw, fc1_b, fc2_w, fc2_b, theta);
    k_sample<<<25088, 256, 0, stream>>>(x, theta, out);
}